// Round 8
// baseline (1026.606 us; speedup 1.0000x reference)
//
#include <hip/hip_runtime.h>
#include <math.h>

constexpr int NB = 2, NN = 2048, NC = 256, NL = 4, NH = 4, ND = 64;
constexpr float EPSV = 1e-5f;
constexpr float LOG2E = 1.44269504088896340736f;

using half8 = __attribute__((ext_vector_type(8))) _Float16;
using half4 = __attribute__((ext_vector_type(4))) _Float16;
using f32x4 = __attribute__((ext_vector_type(4))) float;

__device__ __forceinline__ f32x4 mfma16(half8 a, half8 b, f32x4 c) {
    return __builtin_amdgcn_mfma_f32_16x16x32_f16(a, b, c, 0, 0, 0);
}
__device__ __forceinline__ half8 cvt8(const float* p) {
    float4 x0 = *(const float4*)p, x1 = *(const float4*)(p + 4);
    half8 h;
    h[0]=(_Float16)x0.x; h[1]=(_Float16)x0.y; h[2]=(_Float16)x0.z; h[3]=(_Float16)x0.w;
    h[4]=(_Float16)x1.x; h[5]=(_Float16)x1.y; h[6]=(_Float16)x1.z; h[7]=(_Float16)x1.w;
    return h;
}
// LDS-only barrier: orders ds ops across the workgroup WITHOUT draining
// vmcnt (global loads/stores stay in flight across the barrier). This is
// the R21 lever: __syncthreads() emits s_waitcnt vmcnt(0) lgkmcnt(0) and
// serializes ~200cy of L2 latency into every barrier (m97/AITER lesson).
__device__ __forceinline__ void barrier_lds() {
    asm volatile("s_waitcnt lgkmcnt(0)\n\ts_barrier" ::: "memory");
}

// ---------------------------------------------------------------------------
// out[b][n][o] = epi( sum_k W[o][k] * in[b][n][k] ), K=NC. (validated R7-R14)
// Only used for the first input GEMM (fp32 input).
template<int EPI, bool INF16, bool OUT32>
__global__ __launch_bounds__(256) void gemm_mfma(
    const float* __restrict__ Wg, const float* __restrict__ bias,
    const float* __restrict__ gam, const float* __restrict__ bet,
    const void* __restrict__ inp, void* __restrict__ outp)
{
    int b = blockIdx.x, o0 = blockIdx.y * 64, n0 = blockIdx.z * 32;
    int t = threadIdx.x, w = t >> 6, li = t & 15, qd = (t >> 4) & 3;
    const float* wr = Wg + (size_t)(o0 + w * 16 + li) * NC + qd * 8;
    half8 af[8];
#pragma unroll
    for (int ks = 0; ks < 8; ++ks) af[ks] = cvt8(wr + ks * 32);
    f32x4 acc[2];
    acc[0] = {0.f, 0.f, 0.f, 0.f}; acc[1] = {0.f, 0.f, 0.f, 0.f};
#pragma unroll
    for (int ks = 0; ks < 8; ++ks) {
#pragma unroll
        for (int g = 0; g < 2; ++g) {
            int n = n0 + g * 16 + li;
            half8 bf;
            if (INF16) {
                bf = *(const half8*)((const _Float16*)inp +
                        ((size_t)(b * NN + n) * NC + ks * 32 + qd * 8));
            } else {
                bf = cvt8((const float*)inp + ((size_t)(b * NN + n) * NC + ks * 32 + qd * 8));
            }
            acc[g] = mfma16(af[ks], bf, acc[g]);
        }
    }
    int ob = o0 + w * 16 + qd * 4;
    float4 bs = *(const float4*)(bias + ob);
    float4 gs = {0,0,0,0}, be = {0,0,0,0};
    if (EPI == 1) { gs = *(const float4*)(gam + ob); be = *(const float4*)(bet + ob); }
    float scl = rsqrtf(1.f + EPSV);
#pragma unroll
    for (int g = 0; g < 2; ++g) {
        int n = n0 + g * 16 + li;
        float v4[4];
#pragma unroll
        for (int r = 0; r < 4; ++r) {
            float v = acc[g][r] + ((const float*)&bs)[r];
            if (EPI == 1)
                v = fmaxf(0.f, v * (((const float*)&gs)[r] * scl) + ((const float*)&be)[r]);
            v4[r] = v;
        }
        if (OUT32) {
            float4 fv = {v4[0], v4[1], v4[2], v4[3]};
            *(float4*)((float*)outp + (size_t)(b * NN + n) * NC + ob) = fv;
        } else {
            half4 hv;
#pragma unroll
            for (int r = 0; r < 4; ++r) hv[r] = (_Float16)v4[r];
            *(half4*)((_Float16*)outp + (size_t)(b * NN + n) * NC + ob) = hv;
        }
    }
}

// ---------------------------------------------------------------------------
// Fused (gemm o-slice for head hh) -> [epilogue] -> h16 + LDS tile -> qkv.
// grid (NB*NH, NN/32), block 256. (validated R15/R18)
// R17: q written PRE-SCALED by log2(e). R21: LDS-only mid barrier.
template<int EPI, bool FINAL>
__global__ __launch_bounds__(256) void proj_qkv(
    const float* __restrict__ Wg, const float* __restrict__ bias,
    const float* __restrict__ gam, const float* __restrict__ bet,
    const _Float16* __restrict__ inp,   // [b][n][256] fp16 (hn / MLP1 out)
    _Float16* __restrict__ h16,        // fp16 h out (unused if FINAL)
    float* __restrict__ out32,         // fp32 final out (used if FINAL)
    const float* __restrict__ qw, const float* __restrict__ kw,
    const float* __restrict__ vw, const float* __restrict__ vb,
    _Float16* __restrict__ q16, _Float16* __restrict__ k16,
    _Float16* __restrict__ v16, int lq)
{
    int bh = blockIdx.x, n0 = blockIdx.y * 32;
    int hh = bh & 3, b = bh >> 2;
    __shared__ __align__(16) _Float16 hp[32][72];  // h-tile [n_local][c_local]
    int t = threadIdx.x, w = t >> 6, li = t & 15, qd = (t >> 4) & 3;

    // ---- phase 1: GEMM o-slice = [hh*64, hh*64+64), K = 256 --------------
    const float* wr = Wg + (size_t)(hh * 64 + w * 16 + li) * NC + qd * 8;
    half8 af[8];
#pragma unroll
    for (int ks = 0; ks < 8; ++ks) af[ks] = cvt8(wr + ks * 32);
    f32x4 acc[2];
    acc[0] = {0.f, 0.f, 0.f, 0.f}; acc[1] = {0.f, 0.f, 0.f, 0.f};
#pragma unroll
    for (int ks = 0; ks < 8; ++ks) {
#pragma unroll
        for (int g = 0; g < 2; ++g) {
            int n = n0 + g * 16 + li;
            half8 bf = *(const half8*)(inp + ((size_t)(b * NN + n) * NC + ks * 32 + qd * 8));
            acc[g] = mfma16(af[ks], bf, acc[g]);
        }
    }
    int obl = w * 16 + qd * 4;        // local channel within head [0,64)
    int ob = hh * 64 + obl;           // global channel [0,256)
    float4 bs = *(const float4*)(bias + ob);
    float4 gs = {0,0,0,0}, be = {0,0,0,0};
    if (EPI == 1) { gs = *(const float4*)(gam + ob); be = *(const float4*)(bet + ob); }
    float scl = rsqrtf(1.f + EPSV);
#pragma unroll
    for (int g = 0; g < 2; ++g) {
        int n = n0 + g * 16 + li;
        float v4[4];
#pragma unroll
        for (int r = 0; r < 4; ++r) {
            float v = acc[g][r] + ((const float*)&bs)[r];
            if (EPI == 1)
                v = fmaxf(0.f, v * (((const float*)&gs)[r] * scl) + ((const float*)&be)[r]);
            v4[r] = v;
        }
        if (FINAL) {
            float4 fv = {v4[0], v4[1], v4[2], v4[3]};
            *(float4*)(out32 + (size_t)(b * NN + n) * NC + ob) = fv;
        } else {
            half4 hv;
#pragma unroll
            for (int r = 0; r < 4; ++r) hv[r] = (_Float16)v4[r];
            *(half4*)(h16 + (size_t)(b * NN + n) * NC + ob) = hv;
            *(half4*)(&hp[g * 16 + li][obl]) = hv;
        }
    }
    if (FINAL) return;
    barrier_lds();   // hp visible; h16 global stores stay in flight

    // ---- phase 2: qkv for head hh from the LDS h-tile --------------------
    size_t wbase = (size_t)(lq * NH + hh) * ND * ND;
    size_t wro = (size_t)(w * 16 + li) * ND + qd * 8;
    half8 aq0 = cvt8(qw + wbase + wro), aq1 = cvt8(qw + wbase + wro + 32);
    half8 ak0 = cvt8(kw + wbase + wro), ak1 = cvt8(kw + wbase + wro + 32);
    half8 av0 = cvt8(vw + wbase + wro), av1 = cvt8(vw + wbase + wro + 32);
    f32x4 accq[2], acck[2], accv[2];
#pragma unroll
    for (int g = 0; g < 2; ++g) {
        accq[g] = {0.f,0.f,0.f,0.f}; acck[g] = {0.f,0.f,0.f,0.f}; accv[g] = {0.f,0.f,0.f,0.f};
    }
#pragma unroll
    for (int g = 0; g < 2; ++g) {
        half8 b0 = *(const half8*)(&hp[g * 16 + li][qd * 8]);
        half8 b1 = *(const half8*)(&hp[g * 16 + li][qd * 8 + 32]);
        accq[g] = mfma16(aq0, b0, accq[g]); accq[g] = mfma16(aq1, b1, accq[g]);
        acck[g] = mfma16(ak0, b0, acck[g]); acck[g] = mfma16(ak1, b1, acck[g]);
        accv[g] = mfma16(av0, b0, accv[g]); accv[g] = mfma16(av1, b1, accv[g]);
    }
    int obq = w * 16 + qd * 4;
    _Float16* qo = q16 + (size_t)bh * NN * ND;
    _Float16* ko = k16 + (size_t)bh * NN * ND;
#pragma unroll
    for (int g = 0; g < 2; ++g) {
        int n = n0 + g * 16 + li;
        half4 hq, hk;
#pragma unroll
        for (int r = 0; r < 4; ++r) {
            hq[r] = (_Float16)(accq[g][r] * LOG2E);   // pre-scale for exp2
            hk[r] = (_Float16)acck[g][r];
        }
        *(half4*)(qo + (size_t)n * ND + obq) = hq;
        *(half4*)(ko + (size_t)n * ND + obq) = hk;
    }
    float4 vb4 = *(const float4*)(vb + (size_t)(lq * NH + hh) * ND + obq);
    _Float16* vo = v16 + (size_t)bh * ND * NN;
#pragma unroll
    for (int g = 0; g < 2; ++g) {
        int n = n0 + g * 16 + li;
#pragma unroll
        for (int r = 0; r < 4; ++r)
            vo[(size_t)(obq + r) * NN + n] = (_Float16)(accv[g][r] + ((const float*)&vb4)[r]);
    }
}

// rowsum partials: rowsum_p[ms][bh][n] = sum_{m in ms-range} exp2(S[n,m]).
// grid (8, NN/64, 4), block 256; 8 iters each. (validated R10/R13)
// R20: unroll 2 so K-loads of iter i+1 pipeline under exp2 of iter i.
__global__ __launch_bounds__(256) void rowsum_part(
    const _Float16* __restrict__ qh, const _Float16* __restrict__ kh,
    float* __restrict__ rowsum_p)
{
    int bh = blockIdx.x, nt = blockIdx.y, ms = blockIdx.z;
    const _Float16* qp = qh + (size_t)bh * NN * ND;
    const _Float16* kp = kh + (size_t)bh * NN * ND;
    int t = threadIdx.x, w = t >> 6, li = t & 15, qd = (t >> 4) & 3;
    int nr = nt * 64 + w * 16;
    half8 aq0 = *(const half8*)(qp + (size_t)(nr + li) * ND + qd * 8);
    half8 aq1 = *(const half8*)(qp + (size_t)(nr + li) * ND + qd * 8 + 32);
    float rsacc[4] = {0.f, 0.f, 0.f, 0.f};
#pragma unroll 2
    for (int it = 0; it < 8; ++it) {
        int m0 = ms * 512 + it * 64;
        f32x4 s[4];
#pragma unroll
        for (int g = 0; g < 4; ++g) {
            const _Float16* kb = kp + (size_t)(m0 + g * 16 + li) * ND + qd * 8;
            half8 b0 = *(const half8*)(kb);
            half8 b1 = *(const half8*)(kb + 32);
            s[g] = {0.f, 0.f, 0.f, 0.f};
            s[g] = mfma16(aq0, b0, s[g]);
            s[g] = mfma16(aq1, b1, s[g]);
        }
#pragma unroll
        for (int r = 0; r < 4; ++r)
            rsacc[r] += __builtin_amdgcn_exp2f(s[0][r]) + __builtin_amdgcn_exp2f(s[1][r])
                      + __builtin_amdgcn_exp2f(s[2][r]) + __builtin_amdgcn_exp2f(s[3][r]);
    }
#pragma unroll
    for (int r = 0; r < 4; ++r) {
        float v = rsacc[r];
        v += __shfl_xor(v, 1); v += __shfl_xor(v, 2);
        v += __shfl_xor(v, 4); v += __shfl_xor(v, 8);
        if (li == 0) rowsum_p[((size_t)(ms * NB * NH + bh)) * NN + nr + qd * 4 + r] = v;
    }
}

// attn partials: R18 structure + R20 rotated loop + R21 LDS-only barriers
// (global V/Q loads stay in flight across s_barrier) + setprio around MFMA
// clusters (T5: helps attn-style multi-block phase diversity, m191).
// grid (8, 32, 4), block 256.
__global__ __launch_bounds__(256) void attn_part(
    const _Float16* __restrict__ qh, const _Float16* __restrict__ kh,
    const _Float16* __restrict__ vh, const float* __restrict__ rowsum_p,
    _Float16* __restrict__ xrp16, float* __restrict__ csp)
{
    int bh = blockIdx.x, m0 = blockIdx.y * 64, ns = blockIdx.z;
    const _Float16* qp = qh + (size_t)bh * NN * ND;
    const _Float16* kp = kh + (size_t)bh * NN * ND;
    const _Float16* vp = vh + (size_t)bh * ND * NN;
    __shared__ __align__(16) _Float16 Plds[2][64 * 72];
    __shared__ float cs_wave[4][64];
    __shared__ float irs_lds[512];   // 1/rowsum for this ns slice
    int t = threadIdx.x, w = t >> 6, li = t & 15, qd = (t >> 4) & 3;
    const size_t RSS = (size_t)NB * NH * NN;

    // cooperative irs precompute: 512 rows, 256 threads x 2 (coalesced)
#pragma unroll
    for (int i = 0; i < 2; ++i) {
        int idx = t + i * 256;
        size_t roff = (size_t)bh * NN + ns * 512 + idx;
        float s = rowsum_p[roff] + rowsum_p[RSS + roff]
                + rowsum_p[2 * RSS + roff] + rowsum_p[3 * RSS + roff];
        irs_lds[idx] = 1.f / s;
    }

    half8 bk[4][2];
#pragma unroll
    for (int g = 0; g < 4; ++g) {
        const _Float16* kb = kp + (size_t)(m0 + g * 16 + li) * ND + qd * 8;
        bk[g][0] = *(const half8*)(kb);
        bk[g][1] = *(const half8*)(kb + 32);
    }
    f32x4 acc[4];
#pragma unroll
    for (int g = 0; g < 4; ++g) acc[g] = {0.f, 0.f, 0.f, 0.f};
    float csacc[4] = {0.f, 0.f, 0.f, 0.f};
    const int nb0 = ns * 512;
    const size_t qoff = (size_t)(w * 16 + li) * ND + qd * 8;

    // Q ping-pong: aq[p] holds rows for iteration it with (it&1)==p
    half8 aq[2][2];
    {
        const _Float16* q0 = qp + (size_t)nb0 * ND + qoff;
        const _Float16* q1 = qp + (size_t)(nb0 + 64) * ND + qoff;
        aq[0][0] = *(const half8*)(q0); aq[0][1] = *(const half8*)(q0 + 32);
        aq[1][0] = *(const half8*)(q1); aq[1][1] = *(const half8*)(q1 + 32);
    }
    // prologue: S for it=0
    f32x4 s[4];
#pragma unroll
    for (int g = 0; g < 4; ++g) {
        s[g] = {0.f, 0.f, 0.f, 0.f};
        s[g] = mfma16(aq[0][0], bk[g][0], s[g]);
        s[g] = mfma16(aq[0][1], bk[g][1], s[g]);
    }
    barrier_lds();   // irs_lds ready (K/Q loads stay in flight)

    for (int it = 0; it < 8; ++it) {
        int n0 = nb0 + it * 64;
        _Float16* Pb = Plds[it & 1];
        const _Float16* vrow = vp + (size_t)(w * 16 + li) * NN + n0 + qd * 8;
        half8 av0 = *(const half8*)(vrow);
        half8 av1 = *(const half8*)(vrow + 32);
        float4 ir4 = *(const float4*)&irs_lds[it * 64 + w * 16 + qd * 4];
        // P(it) from current S, write to LDS
#pragma unroll
        for (int g = 0; g < 4; ++g) {
            half4 pv; float lsum = 0.f;
#pragma unroll
            for (int r = 0; r < 4; ++r) {
                float p = __builtin_amdgcn_exp2f(s[g][r]) * ((const float*)&ir4)[r];
                lsum += p;
                pv[r] = (_Float16)p;
            }
            csacc[g] += lsum;
            *(half4*)(&Pb[(g * 16 + li) * 72 + w * 16 + qd * 4]) = pv;
        }
        // QK^T(it+1) before the barrier: fills the barrier-wait bubble with
        // independent MFMA. Uses aq[(it+1)&1]; prefetch q(it+2).
        if (it < 7) {
            if (it < 6) {
                const _Float16* nq = qp + (size_t)(nb0 + (it + 2) * 64) * ND + qoff;
                aq[it & 1][0] = *(const half8*)(nq);
                aq[it & 1][1] = *(const half8*)(nq + 32);
            }
            __builtin_amdgcn_s_setprio(1);
#pragma unroll
            for (int g = 0; g < 4; ++g) {
                f32x4 sn = {0.f, 0.f, 0.f, 0.f};
                sn = mfma16(aq[(it + 1) & 1][0], bk[g][0], sn);
                sn = mfma16(aq[(it + 1) & 1][1], bk[g][1], sn);
                s[g] = sn;
            }
            __builtin_amdgcn_s_setprio(0);
        }
        barrier_lds();   // P(it) visible; V loads NOT drained (R21 lever)
        __builtin_amdgcn_s_setprio(1);
#pragma unroll
        for (int g = 0; g < 4; ++g) {
            half8 b0 = *(const half8*)(&Pb[(g * 16 + li) * 72 + qd * 8]);
            half8 b1 = *(const half8*)(&Pb[(g * 16 + li) * 72 + qd * 8 + 32]);
            acc[g] = mfma16(av0, b0, acc[g]);
            acc[g] = mfma16(av1, b1, acc[g]);
        }
        __builtin_amdgcn_s_setprio(0);
    }
#pragma unroll
    for (int g = 0; g < 4; ++g) {
        float v = csacc[g];
        v += __shfl_xor(v, 16); v += __shfl_xor(v, 32);
        if (qd == 0) cs_wave[w][g * 16 + li] = v;
    }
    __syncthreads();
    if (t < 64) {
        float cs = cs_wave[0][t] + cs_wave[1][t] + cs_wave[2][t] + cs_wave[3][t];
        csp[((size_t)ns * NB * NH + bh) * NN + m0 + t] = cs;
    }
    _Float16* xo = xrp16 + (size_t)ns * ((size_t)NB * NC * NN);
#pragma unroll
    for (int g = 0; g < 4; ++g)
#pragma unroll
        for (int r = 0; r < 4; ++r)
            xo[(size_t)(bh * 64 + w * 16 + qd * 4 + r) * NN + m0 + g * 16 + li] =
                (_Float16)acc[g][r];
}

// Fused: xt[c][n] = (sum_ns xr)[c][n]/(1e-9+sum_ns cs[n]);
// d = h - xt (fp32, from LDS); t = Wt d + tb ; hn = h + relu(bn(t)).
// grid (8, NN/32), block 256. (validated R11; R21: LDS-only barrier)
__global__ __launch_bounds__(256) void delta_fused(
    const float* __restrict__ tw, const float* __restrict__ tb,
    const float* __restrict__ bng, const float* __restrict__ bnb,
    const _Float16* __restrict__ xrp16, const float* __restrict__ csp,
    const _Float16* __restrict__ h16, _Float16* __restrict__ hn16, int l)
{
    int bh = blockIdx.x, n0 = blockIdx.y * 32;
    int hh = bh & 3, b = bh >> 2;
    __shared__ float xt[64][33];   // [c][n_local], normalized xr
    int t = threadIdx.x;
    {   // phase 1: sum slices, normalize, transpose-store
        int xcol = t & 31, yr = t >> 5;
        int m = n0 + xcol;
        const size_t CSS = (size_t)NB * NH * NN;
        float cs = 1e-9f;
#pragma unroll
        for (int sl = 0; sl < 4; ++sl) cs += csp[sl * CSS + (size_t)bh * NN + m];
        float icv = 1.f / cs;
        const size_t XSS = (size_t)NB * NC * NN;
#pragma unroll
        for (int r = 0; r < 8; ++r) {
            int c = yr + 8 * r;
            size_t off = (size_t)(bh * 64 + c) * NN + m;
            float s = 0.f;
#pragma unroll
            for (int sl = 0; sl < 4; ++sl) s += (float)xrp16[sl * XSS + off];
            xt[c][xcol] = s * icv;
        }
    }
    barrier_lds();   // xt visible; no global drain needed
    // phase 2: delta MFMA with B = h - xt built from LDS
    int w = t >> 6, li = t & 15, qd = (t >> 4) & 3;
    const float* wp = tw + (size_t)(l * NH + hh) * ND * ND;
    const float* wr = wp + (size_t)(w * 16 + li) * ND + qd * 8;
    half8 af0 = cvt8(wr), af1 = cvt8(wr + 32);
    f32x4 acc[2];
    acc[0] = {0.f, 0.f, 0.f, 0.f}; acc[1] = {0.f, 0.f, 0.f, 0.f};
#pragma unroll
    for (int g = 0; g < 2; ++g) {
        int nl = g * 16 + li;
        size_t hoff = (size_t)(b * NN + n0 + nl) * NC + hh * 64;
        half8 h0 = *(const half8*)(h16 + hoff + qd * 8);
        half8 h1 = *(const half8*)(h16 + hoff + 32 + qd * 8);
        half8 b0, b1;
#pragma unroll
        for (int j = 0; j < 8; ++j) {
            b0[j] = (_Float16)((float)h0[j] - xt[qd * 8 + j][nl]);
            b1[j] = (_Float16)((float)h1[j] - xt[32 + qd * 8 + j][nl]);
        }
        acc[g] = mfma16(af0, b0, acc[g]);
        acc[g] = mfma16(af1, b1, acc[g]);
    }
    int ob = w * 16 + qd * 4;
    float4 tb4 = *(const float4*)(tb  + (size_t)(l * NH + hh) * ND + ob);
    float4 g4  = *(const float4*)(bng + (size_t)(l * NH + hh) * ND + ob);
    float4 b4  = *(const float4*)(bnb + (size_t)(l * NH + hh) * ND + ob);
    float scl = rsqrtf(1.f + EPSV);
#pragma unroll
    for (int g = 0; g < 2; ++g) {
        int n = n0 + g * 16 + li;
        size_t off = (size_t)(b * NN + n) * NC + hh * 64 + ob;
        half4 h4 = *(const half4*)(h16 + off);
        half4 hv;
#pragma unroll
        for (int r = 0; r < 4; ++r) {
            float tv = acc[g][r] + ((const float*)&tb4)[r];
            float x2 = fmaxf(0.f, tv * (((const float*)&g4)[r] * scl) + ((const float*)&b4)[r]);
            hv[r] = (_Float16)((float)h4[r] + x2);
        }
        *(half4*)(hn16 + off) = hv;
    }
}

extern "C" void kernel_launch(void* const* d_in, const int* in_sizes, int n_in,
                              void* d_out, int out_size, void* d_ws, size_t ws_size,
                              hipStream_t stream)
{
    (void)in_sizes; (void)n_in; (void)out_size; (void)ws_size;
    const float* x      = (const float*)d_in[0];
    const float* in_w1  = (const float*)d_in[1];
    const float* in_b1  = (const float*)d_in[2];
    const float* in_g1  = (const float*)d_in[3];
    const float* in_be1 = (const float*)d_in[4];
    const float* in_w2  = (const float*)d_in[5];
    const float* in_b2  = (const float*)d_in[6];
    const float* in_g2  = (const float*)d_in[7];
    const float* in_be2 = (const float*)d_in[8];
    const float* q_w    = (const float*)d_in[9];
    const float* k_w    = (const float*)d_in[10];
    const float* v_w    = (const float*)d_in[11];
    const float* v_b    = (const float*)d_in[12];
    const float* t_w    = (const float*)d_in[13];
    const float* t_b    = (const float*)d_in[14];
    const float* bn_g   = (const float*)d_in[15];
    const float* bn_b   = (const float*)d_in[16];
    const float* proj_w = (const float*)d_in[17];
    const float* proj_b = (const float*)d_in[18];

    float* ws = (float*)d_ws;
    const size_t M = (size_t)NB * NC * NN;             // 1,048,576
    float* rowsum_p = ws;                              // 4 x 16384 fp32
    float* csp      = ws + 65536;                      // 4 x 16384 fp32
    _Float16* xrp16 = (_Float16*)(ws + 131072);        // 4 x M halfs
    _Float16* hbase = (_Float16*)(ws + 131072 + 2 * M);
    _Float16* h16  = hbase;          // canonical activations [b][n][256]
    _Float16* hA16 = hbase + M;      // MLP1 out / hn
    _Float16* q16  = hbase + 2 * M;  // [bh][n][64], pre-scaled by log2(e)
    _Float16* k16  = hbase + 3 * M;
    _Float16* v16  = hbase + 4 * M;  // [bh][64][n]

    dim3 g1(NB, NC / 64, NN / 32);   // (2,4,64)
    dim3 gf(NB * NH, NN / 32);       // (8,64)

    // MLP1 (fp32 input)
    gemm_mfma<1, false, false><<<g1, 256, 0, stream>>>(in_w1, in_b1, in_g1, in_be1, x, hA16);
    // MLP2 + qkv(l=0) fused
    proj_qkv<1, false><<<gf, 256, 0, stream>>>(
        in_w2, in_b2, in_g2, in_be2, hA16, h16, nullptr,
        q_w, k_w, v_w, v_b, q16, k16, v16, 0);

    for (int l = 0; l < NL; l++) {
        rowsum_part<<<dim3(NB * NH, NN / 64, 4), 256, 0, stream>>>(q16, k16, rowsum_p);
        attn_part<<<dim3(NB * NH, NN / 64, 4), 256, 0, stream>>>(
            q16, k16, v16, rowsum_p, xrp16, csp);
        delta_fused<<<dim3(NB * NH, NN / 32), 256, 0, stream>>>(
            t_w, t_b, bn_g, bn_b, xrp16, csp, h16, hA16, l);
        if (l < NL - 1) {
            // proj(l) + qkv(l+1) fused
            proj_qkv<0, false><<<gf, 256, 0, stream>>>(
                proj_w + (size_t)l * NC * NC, proj_b + (size_t)l * NC,
                nullptr, nullptr, hA16, h16, nullptr,
                q_w, k_w, v_w, v_b, q16, k16, v16, l + 1);
        } else {
            // final proj -> fp32 output, no qkv
            proj_qkv<0, true><<<gf, 256, 0, stream>>>(
                proj_w + (size_t)l * NC * NC, proj_b + (size_t)l * NC,
                nullptr, nullptr, hA16, nullptr, (float*)d_out,
                q_w, k_w, v_w, v_b, q16, k16, v16, 0);
        }
    }
}

// Round 9
// 407.744 us; speedup vs baseline: 2.5178x; 2.5178x over previous
//
#include <hip/hip_runtime.h>
#include <math.h>

constexpr int NB = 2, NN = 2048, NC = 256, NL = 4, NH = 4, ND = 64;
constexpr float EPSV = 1e-5f;
constexpr float LOG2E = 1.44269504088896340736f;

using half8 = __attribute__((ext_vector_type(8))) _Float16;
using half4 = __attribute__((ext_vector_type(4))) _Float16;
using f32x4 = __attribute__((ext_vector_type(4))) float;

__device__ __forceinline__ f32x4 mfma16(half8 a, half8 b, f32x4 c) {
    return __builtin_amdgcn_mfma_f32_16x16x32_f16(a, b, c, 0, 0, 0);
}
__device__ __forceinline__ half8 cvt8(const float* p) {
    float4 x0 = *(const float4*)p, x1 = *(const float4*)(p + 4);
    half8 h;
    h[0]=(_Float16)x0.x; h[1]=(_Float16)x0.y; h[2]=(_Float16)x0.z; h[3]=(_Float16)x0.w;
    h[4]=(_Float16)x1.x; h[5]=(_Float16)x1.y; h[6]=(_Float16)x1.z; h[7]=(_Float16)x1.w;
    return h;
}

// ---------------------------------------------------------------------------
// out[b][n][o] = epi( sum_k W[o][k] * in[b][n][k] ), K=NC. (validated R7-R14)
// Only used for the first input GEMM (fp32 input).
template<int EPI, bool INF16, bool OUT32>
__global__ __launch_bounds__(256) void gemm_mfma(
    const float* __restrict__ Wg, const float* __restrict__ bias,
    const float* __restrict__ gam, const float* __restrict__ bet,
    const void* __restrict__ inp, void* __restrict__ outp)
{
    int b = blockIdx.x, o0 = blockIdx.y * 64, n0 = blockIdx.z * 32;
    int t = threadIdx.x, w = t >> 6, li = t & 15, qd = (t >> 4) & 3;
    const float* wr = Wg + (size_t)(o0 + w * 16 + li) * NC + qd * 8;
    half8 af[8];
#pragma unroll
    for (int ks = 0; ks < 8; ++ks) af[ks] = cvt8(wr + ks * 32);
    f32x4 acc[2];
    acc[0] = {0.f, 0.f, 0.f, 0.f}; acc[1] = {0.f, 0.f, 0.f, 0.f};
#pragma unroll
    for (int ks = 0; ks < 8; ++ks) {
#pragma unroll
        for (int g = 0; g < 2; ++g) {
            int n = n0 + g * 16 + li;
            half8 bf;
            if (INF16) {
                bf = *(const half8*)((const _Float16*)inp +
                        ((size_t)(b * NN + n) * NC + ks * 32 + qd * 8));
            } else {
                bf = cvt8((const float*)inp + ((size_t)(b * NN + n) * NC + ks * 32 + qd * 8));
            }
            acc[g] = mfma16(af[ks], bf, acc[g]);
        }
    }
    int ob = o0 + w * 16 + qd * 4;
    float4 bs = *(const float4*)(bias + ob);
    float4 gs = {0,0,0,0}, be = {0,0,0,0};
    if (EPI == 1) { gs = *(const float4*)(gam + ob); be = *(const float4*)(bet + ob); }
    float scl = rsqrtf(1.f + EPSV);
#pragma unroll
    for (int g = 0; g < 2; ++g) {
        int n = n0 + g * 16 + li;
        float v4[4];
#pragma unroll
        for (int r = 0; r < 4; ++r) {
            float v = acc[g][r] + ((const float*)&bs)[r];
            if (EPI == 1)
                v = fmaxf(0.f, v * (((const float*)&gs)[r] * scl) + ((const float*)&be)[r]);
            v4[r] = v;
        }
        if (OUT32) {
            float4 fv = {v4[0], v4[1], v4[2], v4[3]};
            *(float4*)((float*)outp + (size_t)(b * NN + n) * NC + ob) = fv;
        } else {
            half4 hv;
#pragma unroll
            for (int r = 0; r < 4; ++r) hv[r] = (_Float16)v4[r];
            *(half4*)((_Float16*)outp + (size_t)(b * NN + n) * NC + ob) = hv;
        }
    }
}

// ---------------------------------------------------------------------------
// Fused (gemm o-slice for head hh) -> [epilogue] -> h16 + LDS tile -> qkv.
// grid (NB*NH, NN/32), block 256. (validated R15/R18)
// R17: q written PRE-SCALED by log2(e) so QK consumers use exp2 directly.
// R22: plain __syncthreads() everywhere (R21 asm barrier was a 2.5x
// regression: compiler loses barrier-aware scheduling -> SGPR x2, 40ms
// pathological dispatches. Lever retired.)
template<int EPI, bool FINAL>
__global__ __launch_bounds__(256) void proj_qkv(
    const float* __restrict__ Wg, const float* __restrict__ bias,
    const float* __restrict__ gam, const float* __restrict__ bet,
    const _Float16* __restrict__ inp,   // [b][n][256] fp16 (hn / MLP1 out)
    _Float16* __restrict__ h16,        // fp16 h out (unused if FINAL)
    float* __restrict__ out32,         // fp32 final out (used if FINAL)
    const float* __restrict__ qw, const float* __restrict__ kw,
    const float* __restrict__ vw, const float* __restrict__ vb,
    _Float16* __restrict__ q16, _Float16* __restrict__ k16,
    _Float16* __restrict__ v16, int lq)
{
    int bh = blockIdx.x, n0 = blockIdx.y * 32;
    int hh = bh & 3, b = bh >> 2;
    __shared__ __align__(16) _Float16 hp[32][72];  // h-tile [n_local][c_local]
    int t = threadIdx.x, w = t >> 6, li = t & 15, qd = (t >> 4) & 3;

    // ---- phase 1: GEMM o-slice = [hh*64, hh*64+64), K = 256 --------------
    const float* wr = Wg + (size_t)(hh * 64 + w * 16 + li) * NC + qd * 8;
    half8 af[8];
#pragma unroll
    for (int ks = 0; ks < 8; ++ks) af[ks] = cvt8(wr + ks * 32);
    f32x4 acc[2];
    acc[0] = {0.f, 0.f, 0.f, 0.f}; acc[1] = {0.f, 0.f, 0.f, 0.f};
#pragma unroll
    for (int ks = 0; ks < 8; ++ks) {
#pragma unroll
        for (int g = 0; g < 2; ++g) {
            int n = n0 + g * 16 + li;
            half8 bf = *(const half8*)(inp + ((size_t)(b * NN + n) * NC + ks * 32 + qd * 8));
            acc[g] = mfma16(af[ks], bf, acc[g]);
        }
    }
    int obl = w * 16 + qd * 4;        // local channel within head [0,64)
    int ob = hh * 64 + obl;           // global channel [0,256)
    float4 bs = *(const float4*)(bias + ob);
    float4 gs = {0,0,0,0}, be = {0,0,0,0};
    if (EPI == 1) { gs = *(const float4*)(gam + ob); be = *(const float4*)(bet + ob); }
    float scl = rsqrtf(1.f + EPSV);
#pragma unroll
    for (int g = 0; g < 2; ++g) {
        int n = n0 + g * 16 + li;
        float v4[4];
#pragma unroll
        for (int r = 0; r < 4; ++r) {
            float v = acc[g][r] + ((const float*)&bs)[r];
            if (EPI == 1)
                v = fmaxf(0.f, v * (((const float*)&gs)[r] * scl) + ((const float*)&be)[r]);
            v4[r] = v;
        }
        if (FINAL) {
            float4 fv = {v4[0], v4[1], v4[2], v4[3]};
            *(float4*)(out32 + (size_t)(b * NN + n) * NC + ob) = fv;
        } else {
            half4 hv;
#pragma unroll
            for (int r = 0; r < 4; ++r) hv[r] = (_Float16)v4[r];
            *(half4*)(h16 + (size_t)(b * NN + n) * NC + ob) = hv;
            *(half4*)(&hp[g * 16 + li][obl]) = hv;
        }
    }
    if (FINAL) return;
    __syncthreads();

    // ---- phase 2: qkv for head hh from the LDS h-tile --------------------
    size_t wbase = (size_t)(lq * NH + hh) * ND * ND;
    size_t wro = (size_t)(w * 16 + li) * ND + qd * 8;
    half8 aq0 = cvt8(qw + wbase + wro), aq1 = cvt8(qw + wbase + wro + 32);
    half8 ak0 = cvt8(kw + wbase + wro), ak1 = cvt8(kw + wbase + wro + 32);
    half8 av0 = cvt8(vw + wbase + wro), av1 = cvt8(vw + wbase + wro + 32);
    f32x4 accq[2], acck[2], accv[2];
#pragma unroll
    for (int g = 0; g < 2; ++g) {
        accq[g] = {0.f,0.f,0.f,0.f}; acck[g] = {0.f,0.f,0.f,0.f}; accv[g] = {0.f,0.f,0.f,0.f};
    }
#pragma unroll
    for (int g = 0; g < 2; ++g) {
        half8 b0 = *(const half8*)(&hp[g * 16 + li][qd * 8]);
        half8 b1 = *(const half8*)(&hp[g * 16 + li][qd * 8 + 32]);
        accq[g] = mfma16(aq0, b0, accq[g]); accq[g] = mfma16(aq1, b1, accq[g]);
        acck[g] = mfma16(ak0, b0, acck[g]); acck[g] = mfma16(ak1, b1, acck[g]);
        accv[g] = mfma16(av0, b0, accv[g]); accv[g] = mfma16(av1, b1, accv[g]);
    }
    int obq = w * 16 + qd * 4;
    _Float16* qo = q16 + (size_t)bh * NN * ND;
    _Float16* ko = k16 + (size_t)bh * NN * ND;
#pragma unroll
    for (int g = 0; g < 2; ++g) {
        int n = n0 + g * 16 + li;
        half4 hq, hk;
#pragma unroll
        for (int r = 0; r < 4; ++r) {
            hq[r] = (_Float16)(accq[g][r] * LOG2E);   // pre-scale for exp2
            hk[r] = (_Float16)acck[g][r];
        }
        *(half4*)(qo + (size_t)n * ND + obq) = hq;
        *(half4*)(ko + (size_t)n * ND + obq) = hk;
    }
    float4 vb4 = *(const float4*)(vb + (size_t)(lq * NH + hh) * ND + obq);
    _Float16* vo = v16 + (size_t)bh * ND * NN;
#pragma unroll
    for (int g = 0; g < 2; ++g) {
        int n = n0 + g * 16 + li;
#pragma unroll
        for (int r = 0; r < 4; ++r)
            vo[(size_t)(obq + r) * NN + n] = (_Float16)(accv[g][r] + ((const float*)&vb4)[r]);
    }
}

// rowsum partials: rowsum_p[ms][bh][n] = sum_{m in ms-range} exp2(S[n,m]).
// grid (8, NN/64, 4), block 256; 8 iters each. (validated R10/R13)
// R20: unroll 2 so K-loads of iter i+1 pipeline under exp2 of iter i.
__global__ __launch_bounds__(256) void rowsum_part(
    const _Float16* __restrict__ qh, const _Float16* __restrict__ kh,
    float* __restrict__ rowsum_p)
{
    int bh = blockIdx.x, nt = blockIdx.y, ms = blockIdx.z;
    const _Float16* qp = qh + (size_t)bh * NN * ND;
    const _Float16* kp = kh + (size_t)bh * NN * ND;
    int t = threadIdx.x, w = t >> 6, li = t & 15, qd = (t >> 4) & 3;
    int nr = nt * 64 + w * 16;
    half8 aq0 = *(const half8*)(qp + (size_t)(nr + li) * ND + qd * 8);
    half8 aq1 = *(const half8*)(qp + (size_t)(nr + li) * ND + qd * 8 + 32);
    float rsacc[4] = {0.f, 0.f, 0.f, 0.f};
#pragma unroll 2
    for (int it = 0; it < 8; ++it) {
        int m0 = ms * 512 + it * 64;
        f32x4 s[4];
#pragma unroll
        for (int g = 0; g < 4; ++g) {
            const _Float16* kb = kp + (size_t)(m0 + g * 16 + li) * ND + qd * 8;
            half8 b0 = *(const half8*)(kb);
            half8 b1 = *(const half8*)(kb + 32);
            s[g] = {0.f, 0.f, 0.f, 0.f};
            s[g] = mfma16(aq0, b0, s[g]);
            s[g] = mfma16(aq1, b1, s[g]);
        }
#pragma unroll
        for (int r = 0; r < 4; ++r)
            rsacc[r] += __builtin_amdgcn_exp2f(s[0][r]) + __builtin_amdgcn_exp2f(s[1][r])
                      + __builtin_amdgcn_exp2f(s[2][r]) + __builtin_amdgcn_exp2f(s[3][r]);
    }
#pragma unroll
    for (int r = 0; r < 4; ++r) {
        float v = rsacc[r];
        v += __shfl_xor(v, 1); v += __shfl_xor(v, 2);
        v += __shfl_xor(v, 4); v += __shfl_xor(v, 8);
        if (li == 0) rowsum_p[((size_t)(ms * NB * NH + bh)) * NN + nr + qd * 4 + r] = v;
    }
}

// attn partials: R18 structure + R20 rotated loop (QK^T(it+1) fills the
// barrier-wait bubble; Plds dbuf protects readers). R22: __syncthreads()
// restored (asm barrier retired); setprio around MFMA clusters is the ONE
// isolated change vs the 410.7us R7 champion (T5: +4-7% on attn, m191).
// grid (8, 32, 4), block 256.
__global__ __launch_bounds__(256) void attn_part(
    const _Float16* __restrict__ qh, const _Float16* __restrict__ kh,
    const _Float16* __restrict__ vh, const float* __restrict__ rowsum_p,
    _Float16* __restrict__ xrp16, float* __restrict__ csp)
{
    int bh = blockIdx.x, m0 = blockIdx.y * 64, ns = blockIdx.z;
    const _Float16* qp = qh + (size_t)bh * NN * ND;
    const _Float16* kp = kh + (size_t)bh * NN * ND;
    const _Float16* vp = vh + (size_t)bh * ND * NN;
    __shared__ __align__(16) _Float16 Plds[2][64 * 72];
    __shared__ float cs_wave[4][64];
    __shared__ float irs_lds[512];   // 1/rowsum for this ns slice
    int t = threadIdx.x, w = t >> 6, li = t & 15, qd = (t >> 4) & 3;
    const size_t RSS = (size_t)NB * NH * NN;

    // cooperative irs precompute: 512 rows, 256 threads x 2 (coalesced)
#pragma unroll
    for (int i = 0; i < 2; ++i) {
        int idx = t + i * 256;
        size_t roff = (size_t)bh * NN + ns * 512 + idx;
        float s = rowsum_p[roff] + rowsum_p[RSS + roff]
                + rowsum_p[2 * RSS + roff] + rowsum_p[3 * RSS + roff];
        irs_lds[idx] = 1.f / s;
    }

    half8 bk[4][2];
#pragma unroll
    for (int g = 0; g < 4; ++g) {
        const _Float16* kb = kp + (size_t)(m0 + g * 16 + li) * ND + qd * 8;
        bk[g][0] = *(const half8*)(kb);
        bk[g][1] = *(const half8*)(kb + 32);
    }
    f32x4 acc[4];
#pragma unroll
    for (int g = 0; g < 4; ++g) acc[g] = {0.f, 0.f, 0.f, 0.f};
    float csacc[4] = {0.f, 0.f, 0.f, 0.f};
    const int nb0 = ns * 512;
    const size_t qoff = (size_t)(w * 16 + li) * ND + qd * 8;

    // Q ping-pong: aq[p] holds rows for iteration it with (it&1)==p
    half8 aq[2][2];
    {
        const _Float16* q0 = qp + (size_t)nb0 * ND + qoff;
        const _Float16* q1 = qp + (size_t)(nb0 + 64) * ND + qoff;
        aq[0][0] = *(const half8*)(q0); aq[0][1] = *(const half8*)(q0 + 32);
        aq[1][0] = *(const half8*)(q1); aq[1][1] = *(const half8*)(q1 + 32);
    }
    // prologue: S for it=0
    f32x4 s[4];
#pragma unroll
    for (int g = 0; g < 4; ++g) {
        s[g] = {0.f, 0.f, 0.f, 0.f};
        s[g] = mfma16(aq[0][0], bk[g][0], s[g]);
        s[g] = mfma16(aq[0][1], bk[g][1], s[g]);
    }
    __syncthreads();   // irs_lds ready

    for (int it = 0; it < 8; ++it) {
        int n0 = nb0 + it * 64;
        _Float16* Pb = Plds[it & 1];
        const _Float16* vrow = vp + (size_t)(w * 16 + li) * NN + n0 + qd * 8;
        half8 av0 = *(const half8*)(vrow);
        half8 av1 = *(const half8*)(vrow + 32);
        float4 ir4 = *(const float4*)&irs_lds[it * 64 + w * 16 + qd * 4];
        // P(it) from current S, write to LDS
#pragma unroll
        for (int g = 0; g < 4; ++g) {
            half4 pv; float lsum = 0.f;
#pragma unroll
            for (int r = 0; r < 4; ++r) {
                float p = __builtin_amdgcn_exp2f(s[g][r]) * ((const float*)&ir4)[r];
                lsum += p;
                pv[r] = (_Float16)p;
            }
            csacc[g] += lsum;
            *(half4*)(&Pb[(g * 16 + li) * 72 + w * 16 + qd * 4]) = pv;
        }
        // QK^T(it+1) before the barrier: fills the barrier-wait bubble with
        // independent MFMA. Uses aq[(it+1)&1]; prefetch q(it+2).
        if (it < 7) {
            if (it < 6) {
                const _Float16* nq = qp + (size_t)(nb0 + (it + 2) * 64) * ND + qoff;
                aq[it & 1][0] = *(const half8*)(nq);
                aq[it & 1][1] = *(const half8*)(nq + 32);
            }
            __builtin_amdgcn_s_setprio(1);
#pragma unroll
            for (int g = 0; g < 4; ++g) {
                f32x4 sn = {0.f, 0.f, 0.f, 0.f};
                sn = mfma16(aq[(it + 1) & 1][0], bk[g][0], sn);
                sn = mfma16(aq[(it + 1) & 1][1], bk[g][1], sn);
                s[g] = sn;
            }
            __builtin_amdgcn_s_setprio(0);
        }
        __syncthreads();   // P(it) visible; dbuf protects P(it-1) readers
        __builtin_amdgcn_s_setprio(1);
#pragma unroll
        for (int g = 0; g < 4; ++g) {
            half8 b0 = *(const half8*)(&Pb[(g * 16 + li) * 72 + qd * 8]);
            half8 b1 = *(const half8*)(&Pb[(g * 16 + li) * 72 + qd * 8 + 32]);
            acc[g] = mfma16(av0, b0, acc[g]);
            acc[g] = mfma16(av1, b1, acc[g]);
        }
        __builtin_amdgcn_s_setprio(0);
    }
#pragma unroll
    for (int g = 0; g < 4; ++g) {
        float v = csacc[g];
        v += __shfl_xor(v, 16); v += __shfl_xor(v, 32);
        if (qd == 0) cs_wave[w][g * 16 + li] = v;
    }
    __syncthreads();
    if (t < 64) {
        float cs = cs_wave[0][t] + cs_wave[1][t] + cs_wave[2][t] + cs_wave[3][t];
        csp[((size_t)ns * NB * NH + bh) * NN + m0 + t] = cs;
    }
    _Float16* xo = xrp16 + (size_t)ns * ((size_t)NB * NC * NN);
#pragma unroll
    for (int g = 0; g < 4; ++g)
#pragma unroll
        for (int r = 0; r < 4; ++r)
            xo[(size_t)(bh * 64 + w * 16 + qd * 4 + r) * NN + m0 + g * 16 + li] =
                (_Float16)acc[g][r];
}

// Fused: xt[c][n] = (sum_ns xr)[c][n]/(1e-9+sum_ns cs[n]);
// d = h - xt (fp32, from LDS); t = Wt d + tb ; hn = h + relu(bn(t)).
// grid (8, NN/32), block 256. (correctness-validated in R11; NSPL=4 variant)
__global__ __launch_bounds__(256) void delta_fused(
    const float* __restrict__ tw, const float* __restrict__ tb,
    const float* __restrict__ bng, const float* __restrict__ bnb,
    const _Float16* __restrict__ xrp16, const float* __restrict__ csp,
    const _Float16* __restrict__ h16, _Float16* __restrict__ hn16, int l)
{
    int bh = blockIdx.x, n0 = blockIdx.y * 32;
    int hh = bh & 3, b = bh >> 2;
    __shared__ float xt[64][33];   // [c][n_local], normalized xr
    int t = threadIdx.x;
    {   // phase 1: sum slices, normalize, transpose-store
        int xcol = t & 31, yr = t >> 5;
        int m = n0 + xcol;
        const size_t CSS = (size_t)NB * NH * NN;
        float cs = 1e-9f;
#pragma unroll
        for (int sl = 0; sl < 4; ++sl) cs += csp[sl * CSS + (size_t)bh * NN + m];
        float icv = 1.f / cs;
        const size_t XSS = (size_t)NB * NC * NN;
#pragma unroll
        for (int r = 0; r < 8; ++r) {
            int c = yr + 8 * r;
            size_t off = (size_t)(bh * 64 + c) * NN + m;
            float s = 0.f;
#pragma unroll
            for (int sl = 0; sl < 4; ++sl) s += (float)xrp16[sl * XSS + off];
            xt[c][xcol] = s * icv;
        }
    }
    __syncthreads();
    // phase 2: delta MFMA with B = h - xt built from LDS
    int w = t >> 6, li = t & 15, qd = (t >> 4) & 3;
    const float* wp = tw + (size_t)(l * NH + hh) * ND * ND;
    const float* wr = wp + (size_t)(w * 16 + li) * ND + qd * 8;
    half8 af0 = cvt8(wr), af1 = cvt8(wr + 32);
    f32x4 acc[2];
    acc[0] = {0.f, 0.f, 0.f, 0.f}; acc[1] = {0.f, 0.f, 0.f, 0.f};
#pragma unroll
    for (int g = 0; g < 2; ++g) {
        int nl = g * 16 + li;
        size_t hoff = (size_t)(b * NN + n0 + nl) * NC + hh * 64;
        half8 h0 = *(const half8*)(h16 + hoff + qd * 8);
        half8 h1 = *(const half8*)(h16 + hoff + 32 + qd * 8);
        half8 b0, b1;
#pragma unroll
        for (int j = 0; j < 8; ++j) {
            b0[j] = (_Float16)((float)h0[j] - xt[qd * 8 + j][nl]);
            b1[j] = (_Float16)((float)h1[j] - xt[32 + qd * 8 + j][nl]);
        }
        acc[g] = mfma16(af0, b0, acc[g]);
        acc[g] = mfma16(af1, b1, acc[g]);
    }
    int ob = w * 16 + qd * 4;
    float4 tb4 = *(const float4*)(tb  + (size_t)(l * NH + hh) * ND + ob);
    float4 g4  = *(const float4*)(bng + (size_t)(l * NH + hh) * ND + ob);
    float4 b4  = *(const float4*)(bnb + (size_t)(l * NH + hh) * ND + ob);
    float scl = rsqrtf(1.f + EPSV);
#pragma unroll
    for (int g = 0; g < 2; ++g) {
        int n = n0 + g * 16 + li;
        size_t off = (size_t)(b * NN + n) * NC + hh * 64 + ob;
        half4 h4 = *(const half4*)(h16 + off);
        half4 hv;
#pragma unroll
        for (int r = 0; r < 4; ++r) {
            float tv = acc[g][r] + ((const float*)&tb4)[r];
            float x2 = fmaxf(0.f, tv * (((const float*)&g4)[r] * scl) + ((const float*)&b4)[r]);
            hv[r] = (_Float16)((float)h4[r] + x2);
        }
        *(half4*)(hn16 + off) = hv;
    }
}

extern "C" void kernel_launch(void* const* d_in, const int* in_sizes, int n_in,
                              void* d_out, int out_size, void* d_ws, size_t ws_size,
                              hipStream_t stream)
{
    (void)in_sizes; (void)n_in; (void)out_size; (void)ws_size;
    const float* x      = (const float*)d_in[0];
    const float* in_w1  = (const float*)d_in[1];
    const float* in_b1  = (const float*)d_in[2];
    const float* in_g1  = (const float*)d_in[3];
    const float* in_be1 = (const float*)d_in[4];
    const float* in_w2  = (const float*)d_in[5];
    const float* in_b2  = (const float*)d_in[6];
    const float* in_g2  = (const float*)d_in[7];
    const float* in_be2 = (const float*)d_in[8];
    const float* q_w    = (const float*)d_in[9];
    const float* k_w    = (const float*)d_in[10];
    const float* v_w    = (const float*)d_in[11];
    const float* v_b    = (const float*)d_in[12];
    const float* t_w    = (const float*)d_in[13];
    const float* t_b    = (const float*)d_in[14];
    const float* bn_g   = (const float*)d_in[15];
    const float* bn_b   = (const float*)d_in[16];
    const float* proj_w = (const float*)d_in[17];
    const float* proj_b = (const float*)d_in[18];

    float* ws = (float*)d_ws;
    const size_t M = (size_t)NB * NC * NN;             // 1,048,576
    float* rowsum_p = ws;                              // 4 x 16384 fp32
    float* csp      = ws + 65536;                      // 4 x 16384 fp32
    _Float16* xrp16 = (_Float16*)(ws + 131072);        // 4 x M halfs
    _Float16* hbase = (_Float16*)(ws + 131072 + 2 * M);
    _Float16* h16  = hbase;          // canonical activations [b][n][256]
    _Float16* hA16 = hbase + M;      // MLP1 out / hn
    _Float16* q16  = hbase + 2 * M;  // [bh][n][64], pre-scaled by log2(e)
    _Float16* k16  = hbase + 3 * M;
    _Float16* v16  = hbase + 4 * M;  // [bh][64][n]

    dim3 g1(NB, NC / 64, NN / 32);   // (2,4,64)
    dim3 gf(NB * NH, NN / 32);       // (8,64)

    // MLP1 (fp32 input)
    gemm_mfma<1, false, false><<<g1, 256, 0, stream>>>(in_w1, in_b1, in_g1, in_be1, x, hA16);
    // MLP2 + qkv(l=0) fused
    proj_qkv<1, false><<<gf, 256, 0, stream>>>(
        in_w2, in_b2, in_g2, in_be2, hA16, h16, nullptr,
        q_w, k_w, v_w, v_b, q16, k16, v16, 0);

    for (int l = 0; l < NL; l++) {
        rowsum_part<<<dim3(NB * NH, NN / 64, 4), 256, 0, stream>>>(q16, k16, rowsum_p);
        attn_part<<<dim3(NB * NH, NN / 64, 4), 256, 0, stream>>>(
            q16, k16, v16, rowsum_p, xrp16, csp);
        delta_fused<<<dim3(NB * NH, NN / 32), 256, 0, stream>>>(
            t_w, t_b, bn_g, bn_b, xrp16, csp, h16, hA16, l);
        if (l < NL - 1) {
            // proj(l) + qkv(l+1) fused
            proj_qkv<0, false><<<gf, 256, 0, stream>>>(
                proj_w + (size_t)l * NC * NC, proj_b + (size_t)l * NC,
                nullptr, nullptr, hA16, h16, nullptr,
                q_w, k_w, v_w, v_b, q16, k16, v16, l + 1);
        } else {
            // final proj -> fp32 output, no qkv
            proj_qkv<0, true><<<gf, 256, 0, stream>>>(
                proj_w + (size_t)l * NC * NC, proj_b + (size_t)l * NC,
                nullptr, nullptr, hA16, nullptr, (float*)d_out,
                q_w, k_w, v_w, v_b, q16, k16, v16, 0);
        }
    }
}

// Round 10
// 406.470 us; speedup vs baseline: 2.5257x; 1.0031x over previous
//
#include <hip/hip_runtime.h>
#include <math.h>

constexpr int NB = 2, NN = 2048, NC = 256, NL = 4, NH = 4, ND = 64;
constexpr float EPSV = 1e-5f;
constexpr float LOG2E = 1.44269504088896340736f;

using half8 = __attribute__((ext_vector_type(8))) _Float16;
using half4 = __attribute__((ext_vector_type(4))) _Float16;
using f32x4 = __attribute__((ext_vector_type(4))) float;

__device__ __forceinline__ f32x4 mfma16(half8 a, half8 b, f32x4 c) {
    return __builtin_amdgcn_mfma_f32_16x16x32_f16(a, b, c, 0, 0, 0);
}
__device__ __forceinline__ half8 cvt8(const float* p) {
    float4 x0 = *(const float4*)p, x1 = *(const float4*)(p + 4);
    half8 h;
    h[0]=(_Float16)x0.x; h[1]=(_Float16)x0.y; h[2]=(_Float16)x0.z; h[3]=(_Float16)x0.w;
    h[4]=(_Float16)x1.x; h[5]=(_Float16)x1.y; h[6]=(_Float16)x1.z; h[7]=(_Float16)x1.w;
    return h;
}

// ---------------------------------------------------------------------------
// out[b][n][o] = epi( sum_k W[o][k] * in[b][n][k] ), K=NC. (validated R7-R14)
// Only used for the first input GEMM (fp32 input).
template<int EPI, bool INF16, bool OUT32>
__global__ __launch_bounds__(256) void gemm_mfma(
    const float* __restrict__ Wg, const float* __restrict__ bias,
    const float* __restrict__ gam, const float* __restrict__ bet,
    const void* __restrict__ inp, void* __restrict__ outp)
{
    int b = blockIdx.x, o0 = blockIdx.y * 64, n0 = blockIdx.z * 32;
    int t = threadIdx.x, w = t >> 6, li = t & 15, qd = (t >> 4) & 3;
    const float* wr = Wg + (size_t)(o0 + w * 16 + li) * NC + qd * 8;
    half8 af[8];
#pragma unroll
    for (int ks = 0; ks < 8; ++ks) af[ks] = cvt8(wr + ks * 32);
    f32x4 acc[2];
    acc[0] = {0.f, 0.f, 0.f, 0.f}; acc[1] = {0.f, 0.f, 0.f, 0.f};
#pragma unroll
    for (int ks = 0; ks < 8; ++ks) {
#pragma unroll
        for (int g = 0; g < 2; ++g) {
            int n = n0 + g * 16 + li;
            half8 bf;
            if (INF16) {
                bf = *(const half8*)((const _Float16*)inp +
                        ((size_t)(b * NN + n) * NC + ks * 32 + qd * 8));
            } else {
                bf = cvt8((const float*)inp + ((size_t)(b * NN + n) * NC + ks * 32 + qd * 8));
            }
            acc[g] = mfma16(af[ks], bf, acc[g]);
        }
    }
    int ob = o0 + w * 16 + qd * 4;
    float4 bs = *(const float4*)(bias + ob);
    float4 gs = {0,0,0,0}, be = {0,0,0,0};
    if (EPI == 1) { gs = *(const float4*)(gam + ob); be = *(const float4*)(bet + ob); }
    float scl = rsqrtf(1.f + EPSV);
#pragma unroll
    for (int g = 0; g < 2; ++g) {
        int n = n0 + g * 16 + li;
        float v4[4];
#pragma unroll
        for (int r = 0; r < 4; ++r) {
            float v = acc[g][r] + ((const float*)&bs)[r];
            if (EPI == 1)
                v = fmaxf(0.f, v * (((const float*)&gs)[r] * scl) + ((const float*)&be)[r]);
            v4[r] = v;
        }
        if (OUT32) {
            float4 fv = {v4[0], v4[1], v4[2], v4[3]};
            *(float4*)((float*)outp + (size_t)(b * NN + n) * NC + ob) = fv;
        } else {
            half4 hv;
#pragma unroll
            for (int r = 0; r < 4; ++r) hv[r] = (_Float16)v4[r];
            *(half4*)((_Float16*)outp + (size_t)(b * NN + n) * NC + ob) = hv;
        }
    }
}

// ---------------------------------------------------------------------------
// Fused (gemm o-slice for head hh) -> [epilogue] -> h16 + LDS tile -> qkv.
// grid (NB*NH, NN/32), block 256. (validated R15/R18)
// R17: q written PRE-SCALED by log2(e) so QK consumers use exp2 directly.
template<int EPI, bool FINAL>
__global__ __launch_bounds__(256) void proj_qkv(
    const float* __restrict__ Wg, const float* __restrict__ bias,
    const float* __restrict__ gam, const float* __restrict__ bet,
    const _Float16* __restrict__ inp,   // [b][n][256] fp16 (hn / MLP1 out)
    _Float16* __restrict__ h16,        // fp16 h out (unused if FINAL)
    float* __restrict__ out32,         // fp32 final out (used if FINAL)
    const float* __restrict__ qw, const float* __restrict__ kw,
    const float* __restrict__ vw, const float* __restrict__ vb,
    _Float16* __restrict__ q16, _Float16* __restrict__ k16,
    _Float16* __restrict__ v16, int lq)
{
    int bh = blockIdx.x, n0 = blockIdx.y * 32;
    int hh = bh & 3, b = bh >> 2;
    __shared__ __align__(16) _Float16 hp[32][72];  // h-tile [n_local][c_local]
    int t = threadIdx.x, w = t >> 6, li = t & 15, qd = (t >> 4) & 3;

    // ---- phase 1: GEMM o-slice = [hh*64, hh*64+64), K = 256 --------------
    const float* wr = Wg + (size_t)(hh * 64 + w * 16 + li) * NC + qd * 8;
    half8 af[8];
#pragma unroll
    for (int ks = 0; ks < 8; ++ks) af[ks] = cvt8(wr + ks * 32);
    f32x4 acc[2];
    acc[0] = {0.f, 0.f, 0.f, 0.f}; acc[1] = {0.f, 0.f, 0.f, 0.f};
#pragma unroll
    for (int ks = 0; ks < 8; ++ks) {
#pragma unroll
        for (int g = 0; g < 2; ++g) {
            int n = n0 + g * 16 + li;
            half8 bf = *(const half8*)(inp + ((size_t)(b * NN + n) * NC + ks * 32 + qd * 8));
            acc[g] = mfma16(af[ks], bf, acc[g]);
        }
    }
    int obl = w * 16 + qd * 4;        // local channel within head [0,64)
    int ob = hh * 64 + obl;           // global channel [0,256)
    float4 bs = *(const float4*)(bias + ob);
    float4 gs = {0,0,0,0}, be = {0,0,0,0};
    if (EPI == 1) { gs = *(const float4*)(gam + ob); be = *(const float4*)(bet + ob); }
    float scl = rsqrtf(1.f + EPSV);
#pragma unroll
    for (int g = 0; g < 2; ++g) {
        int n = n0 + g * 16 + li;
        float v4[4];
#pragma unroll
        for (int r = 0; r < 4; ++r) {
            float v = acc[g][r] + ((const float*)&bs)[r];
            if (EPI == 1)
                v = fmaxf(0.f, v * (((const float*)&gs)[r] * scl) + ((const float*)&be)[r]);
            v4[r] = v;
        }
        if (FINAL) {
            float4 fv = {v4[0], v4[1], v4[2], v4[3]};
            *(float4*)(out32 + (size_t)(b * NN + n) * NC + ob) = fv;
        } else {
            half4 hv;
#pragma unroll
            for (int r = 0; r < 4; ++r) hv[r] = (_Float16)v4[r];
            *(half4*)(h16 + (size_t)(b * NN + n) * NC + ob) = hv;
            *(half4*)(&hp[g * 16 + li][obl]) = hv;
        }
    }
    if (FINAL) return;
    __syncthreads();

    // ---- phase 2: qkv for head hh from the LDS h-tile --------------------
    size_t wbase = (size_t)(lq * NH + hh) * ND * ND;
    size_t wro = (size_t)(w * 16 + li) * ND + qd * 8;
    half8 aq0 = cvt8(qw + wbase + wro), aq1 = cvt8(qw + wbase + wro + 32);
    half8 ak0 = cvt8(kw + wbase + wro), ak1 = cvt8(kw + wbase + wro + 32);
    half8 av0 = cvt8(vw + wbase + wro), av1 = cvt8(vw + wbase + wro + 32);
    f32x4 accq[2], acck[2], accv[2];
#pragma unroll
    for (int g = 0; g < 2; ++g) {
        accq[g] = {0.f,0.f,0.f,0.f}; acck[g] = {0.f,0.f,0.f,0.f}; accv[g] = {0.f,0.f,0.f,0.f};
    }
#pragma unroll
    for (int g = 0; g < 2; ++g) {
        half8 b0 = *(const half8*)(&hp[g * 16 + li][qd * 8]);
        half8 b1 = *(const half8*)(&hp[g * 16 + li][qd * 8 + 32]);
        accq[g] = mfma16(aq0, b0, accq[g]); accq[g] = mfma16(aq1, b1, accq[g]);
        acck[g] = mfma16(ak0, b0, acck[g]); acck[g] = mfma16(ak1, b1, acck[g]);
        accv[g] = mfma16(av0, b0, accv[g]); accv[g] = mfma16(av1, b1, accv[g]);
    }
    int obq = w * 16 + qd * 4;
    _Float16* qo = q16 + (size_t)bh * NN * ND;
    _Float16* ko = k16 + (size_t)bh * NN * ND;
#pragma unroll
    for (int g = 0; g < 2; ++g) {
        int n = n0 + g * 16 + li;
        half4 hq, hk;
#pragma unroll
        for (int r = 0; r < 4; ++r) {
            hq[r] = (_Float16)(accq[g][r] * LOG2E);   // pre-scale for exp2
            hk[r] = (_Float16)acck[g][r];
        }
        *(half4*)(qo + (size_t)n * ND + obq) = hq;
        *(half4*)(ko + (size_t)n * ND + obq) = hk;
    }
    float4 vb4 = *(const float4*)(vb + (size_t)(lq * NH + hh) * ND + obq);
    _Float16* vo = v16 + (size_t)bh * ND * NN;
#pragma unroll
    for (int g = 0; g < 2; ++g) {
        int n = n0 + g * 16 + li;
#pragma unroll
        for (int r = 0; r < 4; ++r)
            vo[(size_t)(obq + r) * NN + n] = (_Float16)(accv[g][r] + ((const float*)&vb4)[r]);
    }
}

// rowsum partials: rowsum_p[ms][bh][n] = sum_{m in ms-range} exp2(S[n,m]).
// grid (8, NN/64, 4), block 256; 8 iters each. (validated R10/R13)
// R20: unroll 2 so K-loads of iter i+1 pipeline under exp2 of iter i.
__global__ __launch_bounds__(256) void rowsum_part(
    const _Float16* __restrict__ qh, const _Float16* __restrict__ kh,
    float* __restrict__ rowsum_p)
{
    int bh = blockIdx.x, nt = blockIdx.y, ms = blockIdx.z;
    const _Float16* qp = qh + (size_t)bh * NN * ND;
    const _Float16* kp = kh + (size_t)bh * NN * ND;
    int t = threadIdx.x, w = t >> 6, li = t & 15, qd = (t >> 4) & 3;
    int nr = nt * 64 + w * 16;
    half8 aq0 = *(const half8*)(qp + (size_t)(nr + li) * ND + qd * 8);
    half8 aq1 = *(const half8*)(qp + (size_t)(nr + li) * ND + qd * 8 + 32);
    float rsacc[4] = {0.f, 0.f, 0.f, 0.f};
#pragma unroll 2
    for (int it = 0; it < 8; ++it) {
        int m0 = ms * 512 + it * 64;
        f32x4 s[4];
#pragma unroll
        for (int g = 0; g < 4; ++g) {
            const _Float16* kb = kp + (size_t)(m0 + g * 16 + li) * ND + qd * 8;
            half8 b0 = *(const half8*)(kb);
            half8 b1 = *(const half8*)(kb + 32);
            s[g] = {0.f, 0.f, 0.f, 0.f};
            s[g] = mfma16(aq0, b0, s[g]);
            s[g] = mfma16(aq1, b1, s[g]);
        }
#pragma unroll
        for (int r = 0; r < 4; ++r)
            rsacc[r] += __builtin_amdgcn_exp2f(s[0][r]) + __builtin_amdgcn_exp2f(s[1][r])
                      + __builtin_amdgcn_exp2f(s[2][r]) + __builtin_amdgcn_exp2f(s[3][r]);
    }
#pragma unroll
    for (int r = 0; r < 4; ++r) {
        float v = rsacc[r];
        v += __shfl_xor(v, 1); v += __shfl_xor(v, 2);
        v += __shfl_xor(v, 4); v += __shfl_xor(v, 8);
        if (li == 0) rowsum_p[((size_t)(ms * NB * NH + bh)) * NN + nr + qd * 4 + r] = v;
    }
}

// attn partials: R18 structure + R20 rotated loop (QK^T(it+1) fills the
// barrier-wait bubble; Plds dbuf protects readers) + R22 setprio around MFMA
// clusters (validated: 410.7 -> 407.7). grid (8, 32, 4), block 256.
__global__ __launch_bounds__(256) void attn_part(
    const _Float16* __restrict__ qh, const _Float16* __restrict__ kh,
    const _Float16* __restrict__ vh, const float* __restrict__ rowsum_p,
    _Float16* __restrict__ xrp16, float* __restrict__ csp)
{
    int bh = blockIdx.x, m0 = blockIdx.y * 64, ns = blockIdx.z;
    const _Float16* qp = qh + (size_t)bh * NN * ND;
    const _Float16* kp = kh + (size_t)bh * NN * ND;
    const _Float16* vp = vh + (size_t)bh * ND * NN;
    __shared__ __align__(16) _Float16 Plds[2][64 * 72];
    __shared__ float cs_wave[4][64];
    __shared__ float irs_lds[512];   // 1/rowsum for this ns slice
    int t = threadIdx.x, w = t >> 6, li = t & 15, qd = (t >> 4) & 3;
    const size_t RSS = (size_t)NB * NH * NN;

    // cooperative irs precompute: 512 rows, 256 threads x 2 (coalesced)
#pragma unroll
    for (int i = 0; i < 2; ++i) {
        int idx = t + i * 256;
        size_t roff = (size_t)bh * NN + ns * 512 + idx;
        float s = rowsum_p[roff] + rowsum_p[RSS + roff]
                + rowsum_p[2 * RSS + roff] + rowsum_p[3 * RSS + roff];
        irs_lds[idx] = 1.f / s;
    }

    half8 bk[4][2];
#pragma unroll
    for (int g = 0; g < 4; ++g) {
        const _Float16* kb = kp + (size_t)(m0 + g * 16 + li) * ND + qd * 8;
        bk[g][0] = *(const half8*)(kb);
        bk[g][1] = *(const half8*)(kb + 32);
    }
    f32x4 acc[4];
#pragma unroll
    for (int g = 0; g < 4; ++g) acc[g] = {0.f, 0.f, 0.f, 0.f};
    float csacc[4] = {0.f, 0.f, 0.f, 0.f};
    const int nb0 = ns * 512;
    const size_t qoff = (size_t)(w * 16 + li) * ND + qd * 8;

    // Q ping-pong: aq[p] holds rows for iteration it with (it&1)==p
    half8 aq[2][2];
    {
        const _Float16* q0 = qp + (size_t)nb0 * ND + qoff;
        const _Float16* q1 = qp + (size_t)(nb0 + 64) * ND + qoff;
        aq[0][0] = *(const half8*)(q0); aq[0][1] = *(const half8*)(q0 + 32);
        aq[1][0] = *(const half8*)(q1); aq[1][1] = *(const half8*)(q1 + 32);
    }
    // prologue: S for it=0
    f32x4 s[4];
#pragma unroll
    for (int g = 0; g < 4; ++g) {
        s[g] = {0.f, 0.f, 0.f, 0.f};
        s[g] = mfma16(aq[0][0], bk[g][0], s[g]);
        s[g] = mfma16(aq[0][1], bk[g][1], s[g]);
    }
    __syncthreads();   // irs_lds ready

    for (int it = 0; it < 8; ++it) {
        int n0 = nb0 + it * 64;
        _Float16* Pb = Plds[it & 1];
        const _Float16* vrow = vp + (size_t)(w * 16 + li) * NN + n0 + qd * 8;
        half8 av0 = *(const half8*)(vrow);
        half8 av1 = *(const half8*)(vrow + 32);
        float4 ir4 = *(const float4*)&irs_lds[it * 64 + w * 16 + qd * 4];
        // P(it) from current S, write to LDS
#pragma unroll
        for (int g = 0; g < 4; ++g) {
            half4 pv; float lsum = 0.f;
#pragma unroll
            for (int r = 0; r < 4; ++r) {
                float p = __builtin_amdgcn_exp2f(s[g][r]) * ((const float*)&ir4)[r];
                lsum += p;
                pv[r] = (_Float16)p;
            }
            csacc[g] += lsum;
            *(half4*)(&Pb[(g * 16 + li) * 72 + w * 16 + qd * 4]) = pv;
        }
        // QK^T(it+1) before the barrier: fills the barrier-wait bubble with
        // independent MFMA. Uses aq[(it+1)&1]; prefetch q(it+2).
        if (it < 7) {
            if (it < 6) {
                const _Float16* nq = qp + (size_t)(nb0 + (it + 2) * 64) * ND + qoff;
                aq[it & 1][0] = *(const half8*)(nq);
                aq[it & 1][1] = *(const half8*)(nq + 32);
            }
            __builtin_amdgcn_s_setprio(1);
#pragma unroll
            for (int g = 0; g < 4; ++g) {
                f32x4 sn = {0.f, 0.f, 0.f, 0.f};
                sn = mfma16(aq[(it + 1) & 1][0], bk[g][0], sn);
                sn = mfma16(aq[(it + 1) & 1][1], bk[g][1], sn);
                s[g] = sn;
            }
            __builtin_amdgcn_s_setprio(0);
        }
        __syncthreads();   // P(it) visible; dbuf protects P(it-1) readers
        __builtin_amdgcn_s_setprio(1);
#pragma unroll
        for (int g = 0; g < 4; ++g) {
            half8 b0 = *(const half8*)(&Pb[(g * 16 + li) * 72 + qd * 8]);
            half8 b1 = *(const half8*)(&Pb[(g * 16 + li) * 72 + qd * 8 + 32]);
            acc[g] = mfma16(av0, b0, acc[g]);
            acc[g] = mfma16(av1, b1, acc[g]);
        }
        __builtin_amdgcn_s_setprio(0);
    }
#pragma unroll
    for (int g = 0; g < 4; ++g) {
        float v = csacc[g];
        v += __shfl_xor(v, 16); v += __shfl_xor(v, 32);
        if (qd == 0) cs_wave[w][g * 16 + li] = v;
    }
    __syncthreads();
    if (t < 64) {
        float cs = cs_wave[0][t] + cs_wave[1][t] + cs_wave[2][t] + cs_wave[3][t];
        csp[((size_t)ns * NB * NH + bh) * NN + m0 + t] = cs;
    }
    _Float16* xo = xrp16 + (size_t)ns * ((size_t)NB * NC * NN);
#pragma unroll
    for (int g = 0; g < 4; ++g)
#pragma unroll
        for (int r = 0; r < 4; ++r)
            xo[(size_t)(bh * 64 + w * 16 + qd * 4 + r) * NN + m0 + g * 16 + li] =
                (_Float16)acc[g][r];
}

// Fused: xt[c][n] = (sum_ns xr)[c][n]; icv[n] = 1/(1e-9+sum_ns cs[n]);
// d = h - xt*icv (fp32, from LDS); t = Wt d + tb ; hn = h + relu(bn(t)).
// grid (8, NN/32), block 256.
// R23: phase-1 vectorized — c = t>>2, m-oct = t&3: 4 aligned half8 loads per
// thread (was 32 scalar 2B loads); icv computed by t<32 in parallel and
// applied at phase-2 read (numerically identical: (sum)*icv in f32 either way).
__global__ __launch_bounds__(256) void delta_fused(
    const float* __restrict__ tw, const float* __restrict__ tb,
    const float* __restrict__ bng, const float* __restrict__ bnb,
    const _Float16* __restrict__ xrp16, const float* __restrict__ csp,
    const _Float16* __restrict__ h16, _Float16* __restrict__ hn16, int l)
{
    int bh = blockIdx.x, n0 = blockIdx.y * 32;
    int hh = bh & 3, b = bh >> 2;
    __shared__ float xt[64][33];     // [c][n_local], UNNORMALIZED xr sums
    __shared__ float icv_lds[32];    // 1/(1e-9 + colsum) per n_local
    int t = threadIdx.x;
    if (t < 32) {   // colsum inverse (coalesced, 4 scalar f32 loads)
        int m = n0 + t;
        const size_t CSS = (size_t)NB * NH * NN;
        float cs = 1e-9f;
#pragma unroll
        for (int sl = 0; sl < 4; ++sl) cs += csp[sl * CSS + (size_t)bh * NN + m];
        icv_lds[t] = 1.f / cs;
    }
    {   // phase 1: vectorized slice-sum, c = t>>2 (64 rows), 8 m per thread
        int c = t >> 2, mo = (t & 3) * 8;
        const size_t XSS = (size_t)NB * NC * NN;
        size_t off = (size_t)(bh * 64 + c) * NN + n0 + mo;
        float sum8[8] = {0.f, 0.f, 0.f, 0.f, 0.f, 0.f, 0.f, 0.f};
#pragma unroll
        for (int sl = 0; sl < 4; ++sl) {
            half8 v = *(const half8*)(xrp16 + sl * XSS + off);
#pragma unroll
            for (int j = 0; j < 8; ++j) sum8[j] += (float)v[j];
        }
#pragma unroll
        for (int j = 0; j < 8; ++j) xt[c][mo + j] = sum8[j];
    }
    __syncthreads();
    // phase 2: delta MFMA with B = h - xt*icv built from LDS
    int w = t >> 6, li = t & 15, qd = (t >> 4) & 3;
    const float* wp = tw + (size_t)(l * NH + hh) * ND * ND;
    const float* wr = wp + (size_t)(w * 16 + li) * ND + qd * 8;
    half8 af0 = cvt8(wr), af1 = cvt8(wr + 32);
    f32x4 acc[2];
    acc[0] = {0.f, 0.f, 0.f, 0.f}; acc[1] = {0.f, 0.f, 0.f, 0.f};
#pragma unroll
    for (int g = 0; g < 2; ++g) {
        int nl = g * 16 + li;
        float icv = icv_lds[nl];
        size_t hoff = (size_t)(b * NN + n0 + nl) * NC + hh * 64;
        half8 h0 = *(const half8*)(h16 + hoff + qd * 8);
        half8 h1 = *(const half8*)(h16 + hoff + 32 + qd * 8);
        half8 b0, b1;
#pragma unroll
        for (int j = 0; j < 8; ++j) {
            b0[j] = (_Float16)((float)h0[j] - xt[qd * 8 + j][nl] * icv);
            b1[j] = (_Float16)((float)h1[j] - xt[32 + qd * 8 + j][nl] * icv);
        }
        acc[g] = mfma16(af0, b0, acc[g]);
        acc[g] = mfma16(af1, b1, acc[g]);
    }
    int ob = w * 16 + qd * 4;
    float4 tb4 = *(const float4*)(tb  + (size_t)(l * NH + hh) * ND + ob);
    float4 g4  = *(const float4*)(bng + (size_t)(l * NH + hh) * ND + ob);
    float4 b4  = *(const float4*)(bnb + (size_t)(l * NH + hh) * ND + ob);
    float scl = rsqrtf(1.f + EPSV);
#pragma unroll
    for (int g = 0; g < 2; ++g) {
        int n = n0 + g * 16 + li;
        size_t off = (size_t)(b * NN + n) * NC + hh * 64 + ob;
        half4 h4 = *(const half4*)(h16 + off);
        half4 hv;
#pragma unroll
        for (int r = 0; r < 4; ++r) {
            float tv = acc[g][r] + ((const float*)&tb4)[r];
            float x2 = fmaxf(0.f, tv * (((const float*)&g4)[r] * scl) + ((const float*)&b4)[r]);
            hv[r] = (_Float16)((float)h4[r] + x2);
        }
        *(half4*)(hn16 + off) = hv;
    }
}

extern "C" void kernel_launch(void* const* d_in, const int* in_sizes, int n_in,
                              void* d_out, int out_size, void* d_ws, size_t ws_size,
                              hipStream_t stream)
{
    (void)in_sizes; (void)n_in; (void)out_size; (void)ws_size;
    const float* x      = (const float*)d_in[0];
    const float* in_w1  = (const float*)d_in[1];
    const float* in_b1  = (const float*)d_in[2];
    const float* in_g1  = (const float*)d_in[3];
    const float* in_be1 = (const float*)d_in[4];
    const float* in_w2  = (const float*)d_in[5];
    const float* in_b2  = (const float*)d_in[6];
    const float* in_g2  = (const float*)d_in[7];
    const float* in_be2 = (const float*)d_in[8];
    const float* q_w    = (const float*)d_in[9];
    const float* k_w    = (const float*)d_in[10];
    const float* v_w    = (const float*)d_in[11];
    const float* v_b    = (const float*)d_in[12];
    const float* t_w    = (const float*)d_in[13];
    const float* t_b    = (const float*)d_in[14];
    const float* bn_g   = (const float*)d_in[15];
    const float* bn_b   = (const float*)d_in[16];
    const float* proj_w = (const float*)d_in[17];
    const float* proj_b = (const float*)d_in[18];

    float* ws = (float*)d_ws;
    const size_t M = (size_t)NB * NC * NN;             // 1,048,576
    float* rowsum_p = ws;                              // 4 x 16384 fp32
    float* csp      = ws + 65536;                      // 4 x 16384 fp32
    _Float16* xrp16 = (_Float16*)(ws + 131072);        // 4 x M halfs
    _Float16* hbase = (_Float16*)(ws + 131072 + 2 * M);
    _Float16* h16  = hbase;          // canonical activations [b][n][256]
    _Float16* hA16 = hbase + M;      // MLP1 out / hn
    _Float16* q16  = hbase + 2 * M;  // [bh][n][64], pre-scaled by log2(e)
    _Float16* k16  = hbase + 3 * M;
    _Float16* v16  = hbase + 4 * M;  // [bh][64][n]

    dim3 g1(NB, NC / 64, NN / 32);   // (2,4,64)
    dim3 gf(NB * NH, NN / 32);       // (8,64)

    // MLP1 (fp32 input)
    gemm_mfma<1, false, false><<<g1, 256, 0, stream>>>(in_w1, in_b1, in_g1, in_be1, x, hA16);
    // MLP2 + qkv(l=0) fused
    proj_qkv<1, false><<<gf, 256, 0, stream>>>(
        in_w2, in_b2, in_g2, in_be2, hA16, h16, nullptr,
        q_w, k_w, v_w, v_b, q16, k16, v16, 0);

    for (int l = 0; l < NL; l++) {
        rowsum_part<<<dim3(NB * NH, NN / 64, 4), 256, 0, stream>>>(q16, k16, rowsum_p);
        attn_part<<<dim3(NB * NH, NN / 64, 4), 256, 0, stream>>>(
            q16, k16, v16, rowsum_p, xrp16, csp);
        delta_fused<<<dim3(NB * NH, NN / 32), 256, 0, stream>>>(
            t_w, t_b, bn_g, bn_b, xrp16, csp, h16, hA16, l);
        if (l < NL - 1) {
            // proj(l) + qkv(l+1) fused
            proj_qkv<0, false><<<gf, 256, 0, stream>>>(
                proj_w + (size_t)l * NC * NC, proj_b + (size_t)l * NC,
                nullptr, nullptr, hA16, h16, nullptr,
                q_w, k_w, v_w, v_b, q16, k16, v16, l + 1);
        } else {
            // final proj -> fp32 output, no qkv
            proj_qkv<0, true><<<gf, 256, 0, stream>>>(
                proj_w + (size_t)l * NC * NC, proj_b + (size_t)l * NC,
                nullptr, nullptr, hA16, nullptr, (float*)d_out,
                q_w, k_w, v_w, v_b, q16, k16, v16, 0);
        }
    }
}